// Round 15
// baseline (256.921 us; speedup 1.0000x reference)
//
#include <hip/hip_runtime.h>
#include <hip/hip_bf16.h>
#include <cfloat>

// VecPointNet on MI355X, round 15:
//  - Base = r14 (250.6us, best). Single structural change: ygredbias folded
//    into a fused_kernel prologue (each block redundantly computes its b's
//    biasP/biasD in LDS from `part` + Wg/Ug tails). Kernel boundary provides
//    the global sync; `part` double-buffered (partIn/partOut) to avoid the
//    prologue-read vs phase3-write race. Dispatches 11 -> 7.
//  - knn unchanged (48us, ~2x from instruction floor).

typedef __attribute__((ext_vector_type(8))) short short8;
typedef __attribute__((ext_vector_type(4))) float f32x4;

__device__ __forceinline__ unsigned short f2bf(float f) {
    union { float f; unsigned u; } v; v.f = f;
    unsigned r = v.u + 0x7fffu + ((v.u >> 16) & 1u);
    return (unsigned short)(r >> 16);
}
__device__ __forceinline__ float bf2f(unsigned short h) {
    union { unsigned u; float f; } v; v.u = ((unsigned)h) << 16;
    return v.f;
}

// ---------------- setup: prep (pts4) + weight pack ----------------
__global__ __launch_bounds__(256) void setup_kernel(const float* __restrict__ x,
                                                    float4* __restrict__ pts4,
                                                    const float* __restrict__ Wl,
                                                    const float* __restrict__ Ul,
                                                    const float* __restrict__ Wg,
                                                    const float* __restrict__ Ug,
                                                    const float* __restrict__ Wout,
                                                    unsigned short* __restrict__ Ah,
                                                    unsigned short* __restrict__ Al,
                                                    int N, int B) {
    int t = blockIdx.x * 256 + threadIdx.x;     // 0..327679
    if (t < B * N) {
        int b = t / N, n = t - b * N;
        const float* xb = x + (long)b * 3 * N;
        float px = xb[n], py = xb[N + n], pz = xb[2 * N + n];
        pts4[t] = make_float4(px, py, pz, px * px + py * py + pz * pz);
    }
    int g, r, M; long base;
    if (t < 262144) { g = t >> 15; r = t & 32767; M = 256; base = (long)g << 15; }
    else { int t2 = t - 262144; g = 8 + (t2 >> 14); r = t2 & 16383; M = 128;
           base = 262144 + (long)(g - 8) * 16384; }
    int MF = M >> 4;
    int ks = r / (MF * 512);
    int mf = (r >> 9) % MF;
    int lane = (r >> 3) & 63;
    int j = r & 7;
    int m = mf * 16 + (lane & 15);
    int k = ks * 32 + ((lane >> 4) << 3) + j;
    const float* src; int ldw; int row;
    if (g < 4) {
        ldw = 128; row = m & 127;
        src = (m < 128) ? (Wl + (long)g * 128 * 128) : (Ul + (long)g * 128 * 128);
    } else if (g < 8) {
        ldw = 256; row = m & 127;
        int l = g - 4;
        src = (m < 128) ? (Wg + (long)l * 128 * 256) : (Ug + (long)l * 128 * 256);
    } else {
        ldw = 512; row = m;
        src = Wout + (g - 8) * 128;
    }
    float v = src[(long)row * ldw + k];
    unsigned short h = f2bf(v);
    Ah[base + r] = h;
    Al[base + r] = f2bf(v - bf2f(h));
}

// ---------------- knn (r13): bitonic-init chunk 0, stale-T DPP inserts ----------------
__global__ __launch_bounds__(1024) void knn_kernel(const float4* __restrict__ pts4,
                                                   int* __restrict__ idxOut, int N) {
    __shared__ float4 cbuf[4096];   // 64 KB
    int t = threadIdx.x;
    int tilesPerB = N / 16;
    int b = blockIdx.x / tilesPerB;
    int q = (blockIdx.x % tilesPerB) * 16 + (t >> 6);
    int lane = t & 63;

    for (int i = t; i < N; i += 1024) cbuf[i] = pts4[b * N + i];
    __syncthreads();

    float4 Q = cbuf[q];
    unsigned ku; int ki;                         // lanes 0..15: sorted top-16 list

    // ---- chunk 0: 64-lane bitonic sort on exact key = u*4096 + idx ----
    {
        float4 C = cbuf[lane];
        float dot = Q.x * C.x + Q.y * C.y + Q.z * C.z;
        float d2 = Q.w + C.w - 2.0f * dot;        // same formula as reference
        unsigned u = __float_as_uint(d2);
        u ^= (unsigned)((int)u >> 31) | 0x80000000u;
        double key = (double)u * 4096.0 + (double)lane;
#pragma unroll
        for (int k = 2; k <= 64; k <<= 1) {
#pragma unroll
            for (int j = k >> 1; j > 0; j >>= 1) {
                double other = __shfl_xor(key, j);
                bool takeMin = (((lane & j) == 0) == ((lane & k) == 0));
                double mn = fmin(key, other), mx = fmax(key, other);
                key = takeMin ? mn : mx;
            }
        }
        long long kl = (long long)key;            // exact (key < 2^44)
        ki = (int)(kl & 4095);
        ku = (unsigned)(kl >> 12);
    }
    unsigned Tu = (unsigned)__builtin_amdgcn_readlane((int)ku, 15);

    for (int c0 = 64; c0 < N; c0 += 64) {
        float4 C = cbuf[c0 + lane];
        float dot = Q.x * C.x + Q.y * C.y + Q.z * C.z;
        float d2 = Q.w + C.w - 2.0f * dot;        // same formula as reference
        unsigned u = __float_as_uint(d2);
        u ^= (unsigned)((int)u >> 31) | 0x80000000u;
        int ci = c0 + lane;
        unsigned long long mask = __ballot(u <= Tu);
        while (mask) {
            int src = __ffsll(mask) - 1;
            mask &= mask - 1;
            unsigned vu = (unsigned)__builtin_amdgcn_readlane((int)u, src);
            int      vi = __builtin_amdgcn_readlane(ci, src);
            unsigned kum1 = (unsigned)__builtin_amdgcn_update_dpp(
                                (int)ku, (int)ku, 0x111, 0xF, 0xF, false);
            int      kim1 = __builtin_amdgcn_update_dpp(
                                ki, ki, 0x111, 0xF, 0xF, false);
            if (lane == 0) { kum1 = 0u; kim1 = (-2147483647 - 1); }
            bool lem1 = (vu < kum1) || (vu == kum1 && vi < kim1);  // v < k[j-1]
            bool ltj  = (vu < ku)   || (vu == ku   && vi < ki);    // v < k[j]
            unsigned knu = lem1 ? kum1 : (ltj ? vu : ku);
            int      kni = lem1 ? kim1 : (ltj ? vi : ki);
            if (lane < 16) { ku = knu; ki = kni; }
        }
        Tu = (unsigned)__builtin_amdgcn_readlane((int)ku, 15);
    }
    if (lane < 16) idxOut[(b * N + q) * 16 + lane] = ki;
}

// ---------------- edge + gemm0 merged: edge features -> LDS f0 tile -> MFMA ----------------
__global__ __launch_bounds__(512, 1) void edgegemm0_kernel(
    const float4* __restrict__ pts4, const int* __restrict__ idx,
    const float* __restrict__ Win, const float* __restrict__ Uin,
    const unsigned short* __restrict__ Aph, const unsigned short* __restrict__ Apl,
    unsigned short* __restrict__ Oh, unsigned short* __restrict__ Ol,
    float* __restrict__ part, int N)
{
    __shared__ float4 nbuf[32][16];                 // 8 KB
    __shared__ float4 cpt[32];
    __shared__ unsigned short flds[2][3][2][2048];  // 48 KB, ylds layout
    int t = threadIdx.x;
    int lane = t & 63, w = t >> 6;
    int mg = w >> 1, ng = w & 1;
    int b = blockIdx.x >> 7;
    int tile = blockIdx.x & 127;
    int n0 = tile * 32;

    {
        int pl = t >> 4, k = t & 15;
        int nb = idx[(b * N + n0 + pl) * 16 + k];
        nbuf[pl][k] = pts4[b * N + nb];
        if (t < 32) cpt[t] = pts4[b * N + n0 + t];
    }
    __syncthreads();
    {
        int o = t & 127, grp = t >> 7;
        float w0 = Win[o * 3], w1 = Win[o * 3 + 1], w2 = Win[o * 3 + 2];
        float u0 = Uin[o * 3], u1 = Uin[o * 3 + 1], u2 = Uin[o * 3 + 2];
        for (int pl = grp * 8; pl < grp * 8 + 8; ++pl) {
            float4 c4 = cpt[pl];
            float inv = 1.0f / fmaxf(sqrtf(c4.w), 1e-12f);
            float ax = c4.x * inv, ay = c4.y * inv, az = c4.z * inv;
            float a0 = 0.f, a1 = 0.f, a2 = 0.f;
            for (int k = 0; k < 16; ++k) {
                float4 nb = nbuf[pl][k];
                float cr0 = ay * nb.z - az * nb.y;
                float cr1 = az * nb.x - ax * nb.z;
                float cr2 = ax * nb.y - ay * nb.x;
                float df0 = nb.x - c4.x, df1 = nb.y - c4.y, df2 = nb.z - c4.z;
                float P0 = w0 * cr0 + w1 * df0 + w2 * c4.x;
                float P1 = w0 * cr1 + w1 * df1 + w2 * c4.y;
                float P2 = w0 * cr2 + w1 * df2 + w2 * c4.z;
                float D0 = u0 * cr0 + u1 * df0 + u2 * c4.x;
                float D1 = u0 * cr1 + u1 * df1 + u2 * c4.y;
                float D2 = u0 * cr2 + u1 * df2 + u2 * c4.z;
                float dot = P0 * D0 + P1 * D1 + P2 * D2;
                float dsq = D0 * D0 + D1 * D1 + D2 * D2;
                if (dot < 0.0f) {
                    float s = dot / (dsq + 1e-6f);
                    P0 -= s * D0; P1 -= s * D1; P2 -= s * D2;
                }
                a0 += P0; a1 += P1; a2 += P2;
            }
            float vals[3] = { a0 * (1.0f / 16.0f), a1 * (1.0f / 16.0f), a2 * (1.0f / 16.0f) };
            int ngg = pl >> 4, col = pl & 15;
            int li = ((o >> 3) << 7) + (col << 3) + (o & 7);
#pragma unroll
            for (int c = 0; c < 3; ++c) {
                unsigned short hh = f2bf(vals[c]);
                flds[ngg][c][0][li] = hh;
                flds[ngg][c][1][li] = f2bf(vals[c] - bf2f(hh));
            }
        }
    }
    __syncthreads();

    int ncol = tile * 32 + ng * 16 + (lane & 15);
    f32x4 accP[2][3] = {};
    f32x4 accD[2][3] = {};
#pragma unroll
    for (int ks = 0; ks < 4; ++ks) {
        short8 bh[3], bl[3];
        int li = (((ks << 2) + (lane >> 4)) << 7) + ((lane & 15) << 3);
#pragma unroll
        for (int c = 0; c < 3; ++c) {
            bh[c] = *(const short8*)&flds[ng][c][0][li];
            bl[c] = *(const short8*)&flds[ng][c][1][li];
        }
#pragma unroll
        for (int pi = 0; pi < 2; ++pi) {
            int mf = 2 * mg + pi;
            long aoffP = (((long)ks * 16 + mf) * 64 + lane) * 8;
            short8 ahP = *(const short8*)(Aph + aoffP);
            short8 alP = *(const short8*)(Apl + aoffP);
#pragma unroll
            for (int c = 0; c < 3; ++c) {
                accP[pi][c] = __builtin_amdgcn_mfma_f32_16x16x32_bf16(ahP, bh[c], accP[pi][c], 0, 0, 0);
                accP[pi][c] = __builtin_amdgcn_mfma_f32_16x16x32_bf16(ahP, bl[c], accP[pi][c], 0, 0, 0);
                accP[pi][c] = __builtin_amdgcn_mfma_f32_16x16x32_bf16(alP, bh[c], accP[pi][c], 0, 0, 0);
            }
            long aoffD = (((long)ks * 16 + (8 + mf)) * 64 + lane) * 8;
            short8 ahD = *(const short8*)(Aph + aoffD);
            short8 alD = *(const short8*)(Apl + aoffD);
#pragma unroll
            for (int c = 0; c < 3; ++c) {
                accD[pi][c] = __builtin_amdgcn_mfma_f32_16x16x32_bf16(ahD, bh[c], accD[pi][c], 0, 0, 0);
                accD[pi][c] = __builtin_amdgcn_mfma_f32_16x16x32_bf16(ahD, bl[c], accD[pi][c], 0, 0, 0);
                accD[pi][c] = __builtin_amdgcn_mfma_f32_16x16x32_bf16(alD, bh[c], accD[pi][c], 0, 0, 0);
            }
        }
    }

#pragma unroll
    for (int pi = 0; pi < 2; ++pi) {
        int obase = 32 * mg + 16 * pi + ((lane >> 4) << 2);
        float Pv[3][4];
#pragma unroll
        for (int r = 0; r < 4; ++r) {
            float P[3], D[3];
#pragma unroll
            for (int c = 0; c < 3; ++c) { P[c] = accP[pi][c][r]; D[c] = accD[pi][c][r]; }
            float dot = P[0] * D[0] + P[1] * D[1] + P[2] * D[2];
            float dsq = D[0] * D[0] + D[1] * D[1] + D[2] * D[2];
            if (dot < 0.0f) {
                float s = dot / (dsq + 1e-6f);
                P[0] -= s * D[0]; P[1] -= s * D[1]; P[2] -= s * D[2];
            }
            Pv[0][r] = P[0]; Pv[1][r] = P[1]; Pv[2][r] = P[2];
        }
#pragma unroll
        for (int c = 0; c < 3; ++c) {
            unsigned short hs[4], ls[4];
#pragma unroll
            for (int r = 0; r < 4; ++r) {
                hs[r] = f2bf(Pv[c][r]);
                ls[r] = f2bf(Pv[c][r] - bf2f(hs[r]));
            }
            long ooff = ((long)(b * 3 + c) * N + ncol) * 128 + obase;
            *(ushort4*)(Oh + ooff) = make_ushort4(hs[0], hs[1], hs[2], hs[3]);
            *(ushort4*)(Ol + ooff) = make_ushort4(ls[0], ls[1], ls[2], ls[3]);
        }
#pragma unroll
        for (int c = 0; c < 3; ++c) {
#pragma unroll
            for (int r = 0; r < 4; ++r) {
                float v = Pv[c][r];
                v += __shfl_xor(v, 1);
                v += __shfl_xor(v, 2);
                v += __shfl_xor(v, 4);
                v += __shfl_xor(v, 8);
                if ((lane & 15) == 0)
                    part[((long)(b * 3 + c) * 256 + tile * 2 + ng) * 128 + (obase + r)] = v;
            }
        }
    }
}

// ---------------- fused: [prologue: bias from partIn] -> y2 = LNA(Wg y1+b) [LDS]
//                  -> Wout -> out1; HASNEXT: y1' -> y1 + yg partials (partOut);
//                  else out0 partials (partOut) ----------------
template<bool HASNEXT>
__global__ __launch_bounds__(512, 1) void fused_kernel(
    const unsigned short* __restrict__ Aph, const unsigned short* __restrict__ Apl,
    long aOffG, long aOffOut, long aOffNext,
    unsigned short* __restrict__ y1h, unsigned short* __restrict__ y1l,
    const float* __restrict__ WgL, const float* __restrict__ UgL,
    const float* __restrict__ partIn, float* __restrict__ partOut,
    float* __restrict__ Ofp, int accum)
{
    const int N = 4096;
    __shared__ unsigned short ylds[2][3][2][2048];   // 48 KB
    __shared__ float red2[4][128];                   // 2 KB
    __shared__ float ygs[3][128];                    // 1.5 KB
    __shared__ float biasPs[128][3];                 // 1.5 KB
    __shared__ float biasDs[128][3];                 // 1.5 KB
    int t = threadIdx.x;
    int lane = t & 63, w = t >> 6;
    int mg = w >> 1, ng = w & 1;
    int b = blockIdx.x >> 7;
    int tile = blockIdx.x & 127;
    int ncol = tile * 32 + ng * 16 + (lane & 15);
    int kq = (lane >> 4) << 3;

    // ---------- prologue: yg reduce + bias dot (redundant per block) ----------
    {
        int o = t & 127, g = t >> 7;     // g in 0..3, 64 segs each
        for (int c = 0; c < 3; ++c) {
            float s = 0.f;
            const float* p = partIn + ((long)(b * 3 + c) * 256 + g * 64) * 128 + o;
            for (int seg = 0; seg < 64; ++seg) s += p[(long)seg * 128];
            red2[g][o] = s;
            __syncthreads();
            if (t < 128)
                ygs[c][t] = (red2[0][t] + red2[1][t] + red2[2][t] + red2[3][t]) * (1.0f / 4096.0f);
            __syncthreads();
        }
        if (t < 384) {
            int o = t / 3, c = t - o * 3;
            const float* wrow = WgL + o * 256 + 128;
            const float* urow = UgL + o * 256 + 128;
            float sp = 0.f, sd = 0.f;
            for (int i = 0; i < 128; ++i) {
                float y = ygs[c][i];
                sp = fmaf(wrow[i], y, sp);
                sd = fmaf(urow[i], y, sd);
            }
            biasPs[o][c] = sp; biasDs[o][c] = sd;
        }
    }
    __syncthreads();

    // ---------- phase 1: y2 = LNA(Wg y1 + biasP, Ug y1 + biasD) -> ylds ----------
    {
        f32x4 accP[2][3] = {};
        f32x4 accD[2][3] = {};
        const unsigned short* AhB = Aph + aOffG;
        const unsigned short* AlB = Apl + aOffG;
#pragma unroll
        for (int ks = 0; ks < 4; ++ks) {
            short8 bh[3], bl[3];
#pragma unroll
            for (int c = 0; c < 3; ++c) {
                long boff = ((long)(b * 3 + c) * N + ncol) * 128 + ks * 32 + kq;
                bh[c] = *(const short8*)(y1h + boff);
                bl[c] = *(const short8*)(y1l + boff);
            }
#pragma unroll
            for (int pi = 0; pi < 2; ++pi) {
                int mf = 2 * mg + pi;
                long aoffP = (((long)ks * 16 + mf) * 64 + lane) * 8;
                short8 ahP = *(const short8*)(AhB + aoffP);
                short8 alP = *(const short8*)(AlB + aoffP);
#pragma unroll
                for (int c = 0; c < 3; ++c) {
                    accP[pi][c] = __builtin_amdgcn_mfma_f32_16x16x32_bf16(ahP, bh[c], accP[pi][c], 0, 0, 0);
                    accP[pi][c] = __builtin_amdgcn_mfma_f32_16x16x32_bf16(ahP, bl[c], accP[pi][c], 0, 0, 0);
                    accP[pi][c] = __builtin_amdgcn_mfma_f32_16x16x32_bf16(alP, bh[c], accP[pi][c], 0, 0, 0);
                }
                long aoffD = (((long)ks * 16 + (8 + mf)) * 64 + lane) * 8;
                short8 ahD = *(const short8*)(AhB + aoffD);
                short8 alD = *(const short8*)(AlB + aoffD);
#pragma unroll
                for (int c = 0; c < 3; ++c) {
                    accD[pi][c] = __builtin_amdgcn_mfma_f32_16x16x32_bf16(ahD, bh[c], accD[pi][c], 0, 0, 0);
                    accD[pi][c] = __builtin_amdgcn_mfma_f32_16x16x32_bf16(ahD, bl[c], accD[pi][c], 0, 0, 0);
                    accD[pi][c] = __builtin_amdgcn_mfma_f32_16x16x32_bf16(alD, bh[c], accD[pi][c], 0, 0, 0);
                }
            }
        }
#pragma unroll
        for (int pi = 0; pi < 2; ++pi) {
            int obase = 32 * mg + 16 * pi + ((lane >> 4) << 2);
            float Pv[3][4];
#pragma unroll
            for (int r = 0; r < 4; ++r) {
                int o = obase + r;
                float P[3], D[3];
#pragma unroll
                for (int c = 0; c < 3; ++c) {
                    P[c] = accP[pi][c][r] + biasPs[o][c];
                    D[c] = accD[pi][c][r] + biasDs[o][c];
                }
                float dot = P[0] * D[0] + P[1] * D[1] + P[2] * D[2];
                float dsq = D[0] * D[0] + D[1] * D[1] + D[2] * D[2];
                if (dot < 0.0f) {
                    float s = dot / (dsq + 1e-6f);
                    P[0] -= s * D[0]; P[1] -= s * D[1]; P[2] -= s * D[2];
                }
                Pv[0][r] = P[0]; Pv[1][r] = P[1]; Pv[2][r] = P[2];
            }
#pragma unroll
            for (int c = 0; c < 3; ++c) {
                unsigned short hs[4], ls[4];
#pragma unroll
                for (int r = 0; r < 4; ++r) {
                    hs[r] = f2bf(Pv[c][r]);
                    ls[r] = f2bf(Pv[c][r] - bf2f(hs[r]));
                }
                int li = ((obase >> 3) << 7) + ((lane & 15) << 3) + (obase & 7);
                *(ushort4*)&ylds[ng][c][0][li] = make_ushort4(hs[0], hs[1], hs[2], hs[3]);
                *(ushort4*)&ylds[ng][c][1][li] = make_ushort4(ls[0], ls[1], ls[2], ls[3]);
            }
        }
    }
    __syncthreads();

    // ---------- phase 2: out1 (+)= Wout_l @ y2 ; !HASNEXT: emit out0 partials ----------
    {
        f32x4 accO[2][3] = {};
        const unsigned short* AoH = Aph + aOffOut;
        const unsigned short* AoL = Apl + aOffOut;
#pragma unroll
        for (int ks = 0; ks < 4; ++ks) {
            short8 yh[3], yl[3];
            int li = (((ks << 2) + (lane >> 4)) << 7) + ((lane & 15) << 3);
#pragma unroll
            for (int c = 0; c < 3; ++c) {
                yh[c] = *(const short8*)&ylds[ng][c][0][li];
                yl[c] = *(const short8*)&ylds[ng][c][1][li];
            }
#pragma unroll
            for (int pi = 0; pi < 2; ++pi) {
                int mf = 2 * mg + pi;
                long aoff = (((long)ks * 8 + mf) * 64 + lane) * 8;
                short8 ah = *(const short8*)(AoH + aoff);
                short8 al = *(const short8*)(AoL + aoff);
#pragma unroll
                for (int c = 0; c < 3; ++c) {
                    accO[pi][c] = __builtin_amdgcn_mfma_f32_16x16x32_bf16(ah, yh[c], accO[pi][c], 0, 0, 0);
                    accO[pi][c] = __builtin_amdgcn_mfma_f32_16x16x32_bf16(ah, yl[c], accO[pi][c], 0, 0, 0);
                    accO[pi][c] = __builtin_amdgcn_mfma_f32_16x16x32_bf16(al, yh[c], accO[pi][c], 0, 0, 0);
                }
            }
        }
#pragma unroll
        for (int pi = 0; pi < 2; ++pi) {
            int obase = 32 * mg + 16 * pi + ((lane >> 4) << 2);
            float Ov[3][4];
#pragma unroll
            for (int r = 0; r < 4; ++r) {
                int o = obase + r;
#pragma unroll
                for (int c = 0; c < 3; ++c) {
                    long off = ((long)(b * 128 + o) * 3 + c) * N + ncol;
                    float v = accO[pi][c][r];
                    if (accum) v += Ofp[off];
                    Ofp[off] = v;
                    Ov[c][r] = v;
                }
            }
            if (!HASNEXT) {
#pragma unroll
                for (int c = 0; c < 3; ++c) {
#pragma unroll
                    for (int r = 0; r < 4; ++r) {
                        float v = Ov[c][r];
                        v += __shfl_xor(v, 1);
                        v += __shfl_xor(v, 2);
                        v += __shfl_xor(v, 4);
                        v += __shfl_xor(v, 8);
                        if ((lane & 15) == 0)
                            partOut[((long)(b * 3 + c) * 256 + tile * 2 + ng) * 128 + (obase + r)] = v;
                    }
                }
            }
        }
    }

    // ---------- phase 3 (HASNEXT): y1' = LNA(Wl' y2, Ul' y2) -> y1 + yg partials ----------
    if (HASNEXT) {
        f32x4 accP[2][3] = {};
        f32x4 accD[2][3] = {};
        const unsigned short* AnH = Aph + aOffNext;
        const unsigned short* AnL = Apl + aOffNext;
#pragma unroll
        for (int ks = 0; ks < 4; ++ks) {
            short8 bh[3], bl[3];
            int li = (((ks << 2) + (lane >> 4)) << 7) + ((lane & 15) << 3);
#pragma unroll
            for (int c = 0; c < 3; ++c) {
                bh[c] = *(const short8*)&ylds[ng][c][0][li];
                bl[c] = *(const short8*)&ylds[ng][c][1][li];
            }
#pragma unroll
            for (int pi = 0; pi < 2; ++pi) {
                int mf = 2 * mg + pi;
                long aoffP = (((long)ks * 16 + mf) * 64 + lane) * 8;
                short8 ahP = *(const short8*)(AnH + aoffP);
                short8 alP = *(const short8*)(AnL + aoffP);
#pragma unroll
                for (int c = 0; c < 3; ++c) {
                    accP[pi][c] = __builtin_amdgcn_mfma_f32_16x16x32_bf16(ahP, bh[c], accP[pi][c], 0, 0, 0);
                    accP[pi][c] = __builtin_amdgcn_mfma_f32_16x16x32_bf16(ahP, bl[c], accP[pi][c], 0, 0, 0);
                    accP[pi][c] = __builtin_amdgcn_mfma_f32_16x16x32_bf16(alP, bh[c], accP[pi][c], 0, 0, 0);
                }
                long aoffD = (((long)ks * 16 + (8 + mf)) * 64 + lane) * 8;
                short8 ahD = *(const short8*)(AnH + aoffD);
                short8 alD = *(const short8*)(AnL + aoffD);
#pragma unroll
                for (int c = 0; c < 3; ++c) {
                    accD[pi][c] = __builtin_amdgcn_mfma_f32_16x16x32_bf16(ahD, bh[c], accD[pi][c], 0, 0, 0);
                    accD[pi][c] = __builtin_amdgcn_mfma_f32_16x16x32_bf16(ahD, bl[c], accD[pi][c], 0, 0, 0);
                    accD[pi][c] = __builtin_amdgcn_mfma_f32_16x16x32_bf16(alD, bh[c], accD[pi][c], 0, 0, 0);
                }
            }
        }
#pragma unroll
        for (int pi = 0; pi < 2; ++pi) {
            int obase = 32 * mg + 16 * pi + ((lane >> 4) << 2);
            float Pv[3][4];
#pragma unroll
            for (int r = 0; r < 4; ++r) {
                float P[3], D[3];
#pragma unroll
                for (int c = 0; c < 3; ++c) { P[c] = accP[pi][c][r]; D[c] = accD[pi][c][r]; }
                float dot = P[0] * D[0] + P[1] * D[1] + P[2] * D[2];
                float dsq = D[0] * D[0] + D[1] * D[1] + D[2] * D[2];
                if (dot < 0.0f) {
                    float s = dot / (dsq + 1e-6f);
                    P[0] -= s * D[0]; P[1] -= s * D[1]; P[2] -= s * D[2];
                }
                Pv[0][r] = P[0]; Pv[1][r] = P[1]; Pv[2][r] = P[2];
            }
#pragma unroll
            for (int c = 0; c < 3; ++c) {
                unsigned short hs[4], ls[4];
#pragma unroll
                for (int r = 0; r < 4; ++r) {
                    hs[r] = f2bf(Pv[c][r]);
                    ls[r] = f2bf(Pv[c][r] - bf2f(hs[r]));
                }
                long ooff = ((long)(b * 3 + c) * N + ncol) * 128 + obase;
                *(ushort4*)(y1h + ooff) = make_ushort4(hs[0], hs[1], hs[2], hs[3]);
                *(ushort4*)(y1l + ooff) = make_ushort4(ls[0], ls[1], ls[2], ls[3]);
            }
#pragma unroll
            for (int c = 0; c < 3; ++c) {
#pragma unroll
                for (int r = 0; r < 4; ++r) {
                    float v = Pv[c][r];
                    v += __shfl_xor(v, 1);
                    v += __shfl_xor(v, 2);
                    v += __shfl_xor(v, 4);
                    v += __shfl_xor(v, 8);
                    if ((lane & 15) == 0)
                        partOut[((long)(b * 3 + c) * 256 + tile * 2 + ng) * 128 + (obase + r)] = v;
                }
            }
        }
    }
}

// ---------------- out0 finalize: 6 blocks (b*3+c), 1024 threads ----------------
__global__ __launch_bounds__(1024) void out0red_kernel(const float* __restrict__ part,
                                                       float* __restrict__ out0) {
    __shared__ float red[8][128];
    int bc = blockIdx.x;
    int t = threadIdx.x;
    int o = t & 127, g = t >> 7;
    float s = 0.f;
    for (int seg = g * 32; seg < g * 32 + 32; ++seg)
        s += part[((long)bc * 256 + seg) * 128 + o];
    red[g][o] = s;
    __syncthreads();
    if (t < 128) {
        float r = 0.f;
#pragma unroll
        for (int k = 0; k < 8; ++k) r += red[k][t];
        int b = bc / 3, c = bc % 3;
        out0[((long)(b * 128) + t) * 3 + c] = r * (1.0f / 4096.0f);
    }
}

extern "C" void kernel_launch(void* const* d_in, const int* in_sizes, int n_in,
                              void* d_out, int out_size, void* d_ws, size_t ws_size,
                              hipStream_t stream) {
    const float* x    = (const float*)d_in[0];
    const float* Win  = (const float*)d_in[1];
    const float* Uin  = (const float*)d_in[2];
    const float* Wl   = (const float*)d_in[3];
    const float* Ul   = (const float*)d_in[4];
    const float* Wg   = (const float*)d_in[5];
    const float* Ug   = (const float*)d_in[6];
    const float* Wout = (const float*)d_in[7];

    const int B = 2, N = 4096, H = 128;
    float* out0 = (float*)d_out;                 // (B,128,3) mean
    float* out1 = out0 + (long)B * H * 3;        // (B,128,3,N) fp32

    float* ws = (float*)d_ws;
    long off = 0;
    float4* pts4 = (float4*)ws;                  off += (long)B * N * 4;
    int* idx = (int*)(ws + off);                 off += (long)B * N * 16;
    const long ACT = (long)B * 3 * N * H;        // ushort count
    unsigned short* y1h = (unsigned short*)(ws + off);  off += ACT / 2;
    unsigned short* y1l = (unsigned short*)(ws + off);  off += ACT / 2;
    unsigned short* Aph = (unsigned short*)(ws + off);  off += 327680 / 2;
    unsigned short* Apl = (unsigned short*)(ws + off);  off += 327680 / 2;
    float* partA = ws + off;                     off += 6L * 256 * 128;
    float* partB = ws + off;                     off += 6L * 256 * 128;
    // ~16 MB of workspace

    setup_kernel<<<1280, 256, 0, stream>>>(x, pts4, Wl, Ul, Wg, Ug, Wout, Aph, Apl, N, B);
    knn_kernel<<<B * (N / 16), 1024, 0, stream>>>(pts4, idx, N);

    // edge features + layer-0 input GEMM fused (f0 lives in LDS only); yg partials -> partA
    edgegemm0_kernel<<<256, 512, 0, stream>>>(pts4, idx, Win, Uin,
                                              Aph, Apl, y1h, y1l, partA, N);

    float* pIn = partA;
    float* pOut = partB;
    for (int l = 0; l < 4; ++l) {
        long aG = (long)(4 + l) * 32768;
        long aO = 262144 + (long)l * 16384;
        const float* WgL = Wg + (long)l * H * 256;
        const float* UgL = Ug + (long)l * H * 256;
        if (l < 3) {
            fused_kernel<true><<<256, 512, 0, stream>>>(
                Aph, Apl, aG, aO, (long)(l + 1) * 32768,
                y1h, y1l, WgL, UgL, pIn, pOut, out1, l > 0 ? 1 : 0);
        } else {
            fused_kernel<false><<<256, 512, 0, stream>>>(
                Aph, Apl, aG, aO, 0L,
                y1h, y1l, WgL, UgL, pIn, pOut, out1, 1);
        }
        float* tmp = pIn; pIn = pOut; pOut = tmp;
    }
    // after the loop, pIn points at the buffer fused<false> wrote (out0 partials)
    out0red_kernel<<<6, 1024, 0, stream>>>(pIn, out0);
}

// Round 16
// 231.651 us; speedup vs baseline: 1.1091x; 1.1091x over previous
//
#include <hip/hip_runtime.h>
#include <hip/hip_bf16.h>
#include <cfloat>

// VecPointNet on MI355X, round 16:
//  - Base = r14 (250.6us best; r15's bias-prologue fold regressed and is reverted).
//  - Single change: GEMM-bearing kernels (edgegemm0, fused<>) go from 512 to
//    1024 threads (16 waves/block): each wave owns ONE (P,D) fragment pair for
//    one 16-col half instead of two. Same 256-block grid, same 32-col tiles,
//    same LDS layout and B-reuse; waves/SIMD 2 -> 4, per-wave body halved
//    (~84 live VGPRs, fits the 128 cap that launch_bounds(1024) implies).

typedef __attribute__((ext_vector_type(8))) short short8;
typedef __attribute__((ext_vector_type(4))) float f32x4;

__device__ __forceinline__ unsigned short f2bf(float f) {
    union { float f; unsigned u; } v; v.f = f;
    unsigned r = v.u + 0x7fffu + ((v.u >> 16) & 1u);
    return (unsigned short)(r >> 16);
}
__device__ __forceinline__ float bf2f(unsigned short h) {
    union { unsigned u; float f; } v; v.u = ((unsigned)h) << 16;
    return v.f;
}

// ---------------- setup: prep (pts4) + weight pack ----------------
__global__ __launch_bounds__(256) void setup_kernel(const float* __restrict__ x,
                                                    float4* __restrict__ pts4,
                                                    const float* __restrict__ Wl,
                                                    const float* __restrict__ Ul,
                                                    const float* __restrict__ Wg,
                                                    const float* __restrict__ Ug,
                                                    const float* __restrict__ Wout,
                                                    unsigned short* __restrict__ Ah,
                                                    unsigned short* __restrict__ Al,
                                                    int N, int B) {
    int t = blockIdx.x * 256 + threadIdx.x;     // 0..327679
    if (t < B * N) {
        int b = t / N, n = t - b * N;
        const float* xb = x + (long)b * 3 * N;
        float px = xb[n], py = xb[N + n], pz = xb[2 * N + n];
        pts4[t] = make_float4(px, py, pz, px * px + py * py + pz * pz);
    }
    int g, r, M; long base;
    if (t < 262144) { g = t >> 15; r = t & 32767; M = 256; base = (long)g << 15; }
    else { int t2 = t - 262144; g = 8 + (t2 >> 14); r = t2 & 16383; M = 128;
           base = 262144 + (long)(g - 8) * 16384; }
    int MF = M >> 4;
    int ks = r / (MF * 512);
    int mf = (r >> 9) % MF;
    int lane = (r >> 3) & 63;
    int j = r & 7;
    int m = mf * 16 + (lane & 15);
    int k = ks * 32 + ((lane >> 4) << 3) + j;
    const float* src; int ldw; int row;
    if (g < 4) {
        ldw = 128; row = m & 127;
        src = (m < 128) ? (Wl + (long)g * 128 * 128) : (Ul + (long)g * 128 * 128);
    } else if (g < 8) {
        ldw = 256; row = m & 127;
        int l = g - 4;
        src = (m < 128) ? (Wg + (long)l * 128 * 256) : (Ug + (long)l * 128 * 256);
    } else {
        ldw = 512; row = m;
        src = Wout + (g - 8) * 128;
    }
    float v = src[(long)row * ldw + k];
    unsigned short h = f2bf(v);
    Ah[base + r] = h;
    Al[base + r] = f2bf(v - bf2f(h));
}

// ---------------- knn (r13): bitonic-init chunk 0, stale-T DPP inserts ----------------
__global__ __launch_bounds__(1024) void knn_kernel(const float4* __restrict__ pts4,
                                                   int* __restrict__ idxOut, int N) {
    __shared__ float4 cbuf[4096];   // 64 KB
    int t = threadIdx.x;
    int tilesPerB = N / 16;
    int b = blockIdx.x / tilesPerB;
    int q = (blockIdx.x % tilesPerB) * 16 + (t >> 6);
    int lane = t & 63;

    for (int i = t; i < N; i += 1024) cbuf[i] = pts4[b * N + i];
    __syncthreads();

    float4 Q = cbuf[q];
    unsigned ku; int ki;                         // lanes 0..15: sorted top-16 list

    // ---- chunk 0: 64-lane bitonic sort on exact key = u*4096 + idx ----
    {
        float4 C = cbuf[lane];
        float dot = Q.x * C.x + Q.y * C.y + Q.z * C.z;
        float d2 = Q.w + C.w - 2.0f * dot;        // same formula as reference
        unsigned u = __float_as_uint(d2);
        u ^= (unsigned)((int)u >> 31) | 0x80000000u;
        double key = (double)u * 4096.0 + (double)lane;
#pragma unroll
        for (int k = 2; k <= 64; k <<= 1) {
#pragma unroll
            for (int j = k >> 1; j > 0; j >>= 1) {
                double other = __shfl_xor(key, j);
                bool takeMin = (((lane & j) == 0) == ((lane & k) == 0));
                double mn = fmin(key, other), mx = fmax(key, other);
                key = takeMin ? mn : mx;
            }
        }
        long long kl = (long long)key;            // exact (key < 2^44)
        ki = (int)(kl & 4095);
        ku = (unsigned)(kl >> 12);
    }
    unsigned Tu = (unsigned)__builtin_amdgcn_readlane((int)ku, 15);

    for (int c0 = 64; c0 < N; c0 += 64) {
        float4 C = cbuf[c0 + lane];
        float dot = Q.x * C.x + Q.y * C.y + Q.z * C.z;
        float d2 = Q.w + C.w - 2.0f * dot;        // same formula as reference
        unsigned u = __float_as_uint(d2);
        u ^= (unsigned)((int)u >> 31) | 0x80000000u;
        int ci = c0 + lane;
        unsigned long long mask = __ballot(u <= Tu);
        while (mask) {
            int src = __ffsll(mask) - 1;
            mask &= mask - 1;
            unsigned vu = (unsigned)__builtin_amdgcn_readlane((int)u, src);
            int      vi = __builtin_amdgcn_readlane(ci, src);
            unsigned kum1 = (unsigned)__builtin_amdgcn_update_dpp(
                                (int)ku, (int)ku, 0x111, 0xF, 0xF, false);
            int      kim1 = __builtin_amdgcn_update_dpp(
                                ki, ki, 0x111, 0xF, 0xF, false);
            if (lane == 0) { kum1 = 0u; kim1 = (-2147483647 - 1); }
            bool lem1 = (vu < kum1) || (vu == kum1 && vi < kim1);  // v < k[j-1]
            bool ltj  = (vu < ku)   || (vu == ku   && vi < ki);    // v < k[j]
            unsigned knu = lem1 ? kum1 : (ltj ? vu : ku);
            int      kni = lem1 ? kim1 : (ltj ? vi : ki);
            if (lane < 16) { ku = knu; ki = kni; }
        }
        Tu = (unsigned)__builtin_amdgcn_readlane((int)ku, 15);
    }
    if (lane < 16) idxOut[(b * N + q) * 16 + lane] = ki;
}

// ---------------- edge + gemm0 merged, 1024 threads (16 waves, 1 frag-pair/wave) ----------------
__global__ __launch_bounds__(1024) void edgegemm0_kernel(
    const float4* __restrict__ pts4, const int* __restrict__ idx,
    const float* __restrict__ Win, const float* __restrict__ Uin,
    const unsigned short* __restrict__ Aph, const unsigned short* __restrict__ Apl,
    unsigned short* __restrict__ Oh, unsigned short* __restrict__ Ol,
    float* __restrict__ part, int N)
{
    __shared__ float4 nbuf[32][16];                 // 8 KB
    __shared__ float4 cpt[32];
    __shared__ unsigned short flds[2][3][2][2048];  // 48 KB, ylds layout
    int t = threadIdx.x;
    int lane = t & 63, w = t >> 6;                  // w 0..15
    int ng = w >> 3, wv = w & 7;
    int b = blockIdx.x >> 7;
    int tile = blockIdx.x & 127;
    int n0 = tile * 32;

    // ---- phase E: stage neighbors + centers ----
    if (t < 512) {
        int pl = t >> 4, k = t & 15;
        int nb = idx[(b * N + n0 + pl) * 16 + k];
        nbuf[pl][k] = pts4[b * N + nb];
    } else if (t < 544) {
        cpt[t - 512] = pts4[b * N + n0 + (t - 512)];
    }
    __syncthreads();
    {
        int o = t & 127, grp = t >> 7;              // grp 0..7, 4 points each
        float w0 = Win[o * 3], w1 = Win[o * 3 + 1], w2 = Win[o * 3 + 2];
        float u0 = Uin[o * 3], u1 = Uin[o * 3 + 1], u2 = Uin[o * 3 + 2];
        for (int pl = grp * 4; pl < grp * 4 + 4; ++pl) {
            float4 c4 = cpt[pl];
            float inv = 1.0f / fmaxf(sqrtf(c4.w), 1e-12f);
            float ax = c4.x * inv, ay = c4.y * inv, az = c4.z * inv;
            float a0 = 0.f, a1 = 0.f, a2 = 0.f;
            for (int k = 0; k < 16; ++k) {
                float4 nb = nbuf[pl][k];
                float cr0 = ay * nb.z - az * nb.y;
                float cr1 = az * nb.x - ax * nb.z;
                float cr2 = ax * nb.y - ay * nb.x;
                float df0 = nb.x - c4.x, df1 = nb.y - c4.y, df2 = nb.z - c4.z;
                float P0 = w0 * cr0 + w1 * df0 + w2 * c4.x;
                float P1 = w0 * cr1 + w1 * df1 + w2 * c4.y;
                float P2 = w0 * cr2 + w1 * df2 + w2 * c4.z;
                float D0 = u0 * cr0 + u1 * df0 + u2 * c4.x;
                float D1 = u0 * cr1 + u1 * df1 + u2 * c4.y;
                float D2 = u0 * cr2 + u1 * df2 + u2 * c4.z;
                float dot = P0 * D0 + P1 * D1 + P2 * D2;
                float dsq = D0 * D0 + D1 * D1 + D2 * D2;
                if (dot < 0.0f) {
                    float s = dot / (dsq + 1e-6f);
                    P0 -= s * D0; P1 -= s * D1; P2 -= s * D2;
                }
                a0 += P0; a1 += P1; a2 += P2;
            }
            float vals[3] = { a0 * (1.0f / 16.0f), a1 * (1.0f / 16.0f), a2 * (1.0f / 16.0f) };
            int ngg = pl >> 4, col = pl & 15;
            int li = ((o >> 3) << 7) + (col << 3) + (o & 7);
#pragma unroll
            for (int c = 0; c < 3; ++c) {
                unsigned short hh = f2bf(vals[c]);
                flds[ngg][c][0][li] = hh;
                flds[ngg][c][1][li] = f2bf(vals[c] - bf2f(hh));
            }
        }
    }
    __syncthreads();

    // ---- phase G: y1 = LNA(Wl0 f0, Ul0 f0) + yg partials (B from flds) ----
    int ncol = tile * 32 + ng * 16 + (lane & 15);
    f32x4 accP[3] = {};
    f32x4 accD[3] = {};
#pragma unroll
    for (int ks = 0; ks < 4; ++ks) {
        short8 bh[3], bl[3];
        int li = (((ks << 2) + (lane >> 4)) << 7) + ((lane & 15) << 3);
#pragma unroll
        for (int c = 0; c < 3; ++c) {
            bh[c] = *(const short8*)&flds[ng][c][0][li];
            bl[c] = *(const short8*)&flds[ng][c][1][li];
        }
        long aoffP = (((long)ks * 16 + wv) * 64 + lane) * 8;
        short8 ahP = *(const short8*)(Aph + aoffP);
        short8 alP = *(const short8*)(Apl + aoffP);
#pragma unroll
        for (int c = 0; c < 3; ++c) {
            accP[c] = __builtin_amdgcn_mfma_f32_16x16x32_bf16(ahP, bh[c], accP[c], 0, 0, 0);
            accP[c] = __builtin_amdgcn_mfma_f32_16x16x32_bf16(ahP, bl[c], accP[c], 0, 0, 0);
            accP[c] = __builtin_amdgcn_mfma_f32_16x16x32_bf16(alP, bh[c], accP[c], 0, 0, 0);
        }
        long aoffD = (((long)ks * 16 + 8 + wv) * 64 + lane) * 8;
        short8 ahD = *(const short8*)(Aph + aoffD);
        short8 alD = *(const short8*)(Apl + aoffD);
#pragma unroll
        for (int c = 0; c < 3; ++c) {
            accD[c] = __builtin_amdgcn_mfma_f32_16x16x32_bf16(ahD, bh[c], accD[c], 0, 0, 0);
            accD[c] = __builtin_amdgcn_mfma_f32_16x16x32_bf16(ahD, bl[c], accD[c], 0, 0, 0);
            accD[c] = __builtin_amdgcn_mfma_f32_16x16x32_bf16(alD, bh[c], accD[c], 0, 0, 0);
        }
    }

    int obase = 16 * wv + ((lane >> 4) << 2);
    float Pv[3][4];
#pragma unroll
    for (int r = 0; r < 4; ++r) {
        float P[3], D[3];
#pragma unroll
        for (int c = 0; c < 3; ++c) { P[c] = accP[c][r]; D[c] = accD[c][r]; }
        float dot = P[0] * D[0] + P[1] * D[1] + P[2] * D[2];
        float dsq = D[0] * D[0] + D[1] * D[1] + D[2] * D[2];
        if (dot < 0.0f) {
            float s = dot / (dsq + 1e-6f);
            P[0] -= s * D[0]; P[1] -= s * D[1]; P[2] -= s * D[2];
        }
        Pv[0][r] = P[0]; Pv[1][r] = P[1]; Pv[2][r] = P[2];
    }
#pragma unroll
    for (int c = 0; c < 3; ++c) {
        unsigned short hs[4], ls[4];
#pragma unroll
        for (int r = 0; r < 4; ++r) {
            hs[r] = f2bf(Pv[c][r]);
            ls[r] = f2bf(Pv[c][r] - bf2f(hs[r]));
        }
        long ooff = ((long)(b * 3 + c) * N + ncol) * 128 + obase;
        *(ushort4*)(Oh + ooff) = make_ushort4(hs[0], hs[1], hs[2], hs[3]);
        *(ushort4*)(Ol + ooff) = make_ushort4(ls[0], ls[1], ls[2], ls[3]);
#pragma unroll
        for (int r = 0; r < 4; ++r) {
            float v = Pv[c][r];
            v += __shfl_xor(v, 1);
            v += __shfl_xor(v, 2);
            v += __shfl_xor(v, 4);
            v += __shfl_xor(v, 8);
            if ((lane & 15) == 0)
                part[((long)(b * 3 + c) * 256 + tile * 2 + ng) * 128 + (obase + r)] = v;
        }
    }
}

// ---------------- fused, 1024 threads (16 waves, 1 frag-pair/wave) ----------------
template<bool HASNEXT>
__global__ __launch_bounds__(1024) void fused_kernel(
    const unsigned short* __restrict__ Aph, const unsigned short* __restrict__ Apl,
    long aOffG, long aOffOut, long aOffNext,
    unsigned short* __restrict__ y1h, unsigned short* __restrict__ y1l,
    const float* __restrict__ biasP, const float* __restrict__ biasD,
    float* __restrict__ Ofp, float* __restrict__ part, int accum)
{
    const int N = 4096;
    __shared__ unsigned short ylds[2][3][2][2048];   // 48 KB
    int t = threadIdx.x;
    int lane = t & 63, w = t >> 6;                   // w 0..15
    int ng = w >> 3, wv = w & 7;
    int b = blockIdx.x >> 7;
    int tile = blockIdx.x & 127;
    int ncol = tile * 32 + ng * 16 + (lane & 15);
    int kq = (lane >> 4) << 3;

    // ---------- phase 1: y2 = LNA(Wg y1 + biasP, Ug y1 + biasD) -> ylds ----------
    {
        f32x4 accP[3] = {};
        f32x4 accD[3] = {};
        const unsigned short* AhB = Aph + aOffG;
        const unsigned short* AlB = Apl + aOffG;
#pragma unroll
        for (int ks = 0; ks < 4; ++ks) {
            short8 bh[3], bl[3];
#pragma unroll
            for (int c = 0; c < 3; ++c) {
                long boff = ((long)(b * 3 + c) * N + ncol) * 128 + ks * 32 + kq;
                bh[c] = *(const short8*)(y1h + boff);
                bl[c] = *(const short8*)(y1l + boff);
            }
            long aoffP = (((long)ks * 16 + wv) * 64 + lane) * 8;
            short8 ahP = *(const short8*)(AhB + aoffP);
            short8 alP = *(const short8*)(AlB + aoffP);
#pragma unroll
            for (int c = 0; c < 3; ++c) {
                accP[c] = __builtin_amdgcn_mfma_f32_16x16x32_bf16(ahP, bh[c], accP[c], 0, 0, 0);
                accP[c] = __builtin_amdgcn_mfma_f32_16x16x32_bf16(ahP, bl[c], accP[c], 0, 0, 0);
                accP[c] = __builtin_amdgcn_mfma_f32_16x16x32_bf16(alP, bh[c], accP[c], 0, 0, 0);
            }
            long aoffD = (((long)ks * 16 + 8 + wv) * 64 + lane) * 8;
            short8 ahD = *(const short8*)(AhB + aoffD);
            short8 alD = *(const short8*)(AlB + aoffD);
#pragma unroll
            for (int c = 0; c < 3; ++c) {
                accD[c] = __builtin_amdgcn_mfma_f32_16x16x32_bf16(ahD, bh[c], accD[c], 0, 0, 0);
                accD[c] = __builtin_amdgcn_mfma_f32_16x16x32_bf16(ahD, bl[c], accD[c], 0, 0, 0);
                accD[c] = __builtin_amdgcn_mfma_f32_16x16x32_bf16(alD, bh[c], accD[c], 0, 0, 0);
            }
        }
        int obase = 16 * wv + ((lane >> 4) << 2);
        float Pv[3][4];
#pragma unroll
        for (int r = 0; r < 4; ++r) {
            int o = obase + r;
            float P[3], D[3];
#pragma unroll
            for (int c = 0; c < 3; ++c) {
                long bb = ((long)(b * 128 + o)) * 3 + c;
                P[c] = accP[c][r] + biasP[bb];
                D[c] = accD[c][r] + biasD[bb];
            }
            float dot = P[0] * D[0] + P[1] * D[1] + P[2] * D[2];
            float dsq = D[0] * D[0] + D[1] * D[1] + D[2] * D[2];
            if (dot < 0.0f) {
                float s = dot / (dsq + 1e-6f);
                P[0] -= s * D[0]; P[1] -= s * D[1]; P[2] -= s * D[2];
            }
            Pv[0][r] = P[0]; Pv[1][r] = P[1]; Pv[2][r] = P[2];
        }
#pragma unroll
        for (int c = 0; c < 3; ++c) {
            unsigned short hs[4], ls[4];
#pragma unroll
            for (int r = 0; r < 4; ++r) {
                hs[r] = f2bf(Pv[c][r]);
                ls[r] = f2bf(Pv[c][r] - bf2f(hs[r]));
            }
            int li = ((obase >> 3) << 7) + ((lane & 15) << 3) + (obase & 7);
            *(ushort4*)&ylds[ng][c][0][li] = make_ushort4(hs[0], hs[1], hs[2], hs[3]);
            *(ushort4*)&ylds[ng][c][1][li] = make_ushort4(ls[0], ls[1], ls[2], ls[3]);
        }
    }
    __syncthreads();

    // ---------- phase 2: out1 (+)= Wout_l @ y2 ; !HASNEXT: emit out0 partials ----------
    {
        f32x4 accO[3] = {};
        const unsigned short* AoH = Aph + aOffOut;
        const unsigned short* AoL = Apl + aOffOut;
#pragma unroll
        for (int ks = 0; ks < 4; ++ks) {
            short8 yh[3], yl[3];
            int li = (((ks << 2) + (lane >> 4)) << 7) + ((lane & 15) << 3);
#pragma unroll
            for (int c = 0; c < 3; ++c) {
                yh[c] = *(const short8*)&ylds[ng][c][0][li];
                yl[c] = *(const short8*)&ylds[ng][c][1][li];
            }
            long aoff = (((long)ks * 8 + wv) * 64 + lane) * 8;
            short8 ah = *(const short8*)(AoH + aoff);
            short8 al = *(const short8*)(AoL + aoff);
#pragma unroll
            for (int c = 0; c < 3; ++c) {
                accO[c] = __builtin_amdgcn_mfma_f32_16x16x32_bf16(ah, yh[c], accO[c], 0, 0, 0);
                accO[c] = __builtin_amdgcn_mfma_f32_16x16x32_bf16(ah, yl[c], accO[c], 0, 0, 0);
                accO[c] = __builtin_amdgcn_mfma_f32_16x16x32_bf16(al, yh[c], accO[c], 0, 0, 0);
            }
        }
        int obase = 16 * wv + ((lane >> 4) << 2);
        float Ov[3][4];
#pragma unroll
        for (int r = 0; r < 4; ++r) {
            int o = obase + r;
#pragma unroll
            for (int c = 0; c < 3; ++c) {
                long off = ((long)(b * 128 + o) * 3 + c) * N + ncol;
                float v = accO[c][r];
                if (accum) v += Ofp[off];
                Ofp[off] = v;
                Ov[c][r] = v;
            }
        }
        if (!HASNEXT) {
#pragma unroll
            for (int c = 0; c < 3; ++c) {
#pragma unroll
                for (int r = 0; r < 4; ++r) {
                    float v = Ov[c][r];
                    v += __shfl_xor(v, 1);
                    v += __shfl_xor(v, 2);
                    v += __shfl_xor(v, 4);
                    v += __shfl_xor(v, 8);
                    if ((lane & 15) == 0)
                        part[((long)(b * 3 + c) * 256 + tile * 2 + ng) * 128 + (obase + r)] = v;
                }
            }
        }
    }

    // ---------- phase 3 (HASNEXT): y1' = LNA(Wl' y2, Ul' y2) -> y1 + yg partials ----------
    if (HASNEXT) {
        f32x4 accP[3] = {};
        f32x4 accD[3] = {};
        const unsigned short* AnH = Aph + aOffNext;
        const unsigned short* AnL = Apl + aOffNext;
#pragma unroll
        for (int ks = 0; ks < 4; ++ks) {
            short8 bh[3], bl[3];
            int li = (((ks << 2) + (lane >> 4)) << 7) + ((lane & 15) << 3);
#pragma unroll
            for (int c = 0; c < 3; ++c) {
                bh[c] = *(const short8*)&ylds[ng][c][0][li];
                bl[c] = *(const short8*)&ylds[ng][c][1][li];
            }
            long aoffP = (((long)ks * 16 + wv) * 64 + lane) * 8;
            short8 ahP = *(const short8*)(AnH + aoffP);
            short8 alP = *(const short8*)(AnL + aoffP);
#pragma unroll
            for (int c = 0; c < 3; ++c) {
                accP[c] = __builtin_amdgcn_mfma_f32_16x16x32_bf16(ahP, bh[c], accP[c], 0, 0, 0);
                accP[c] = __builtin_amdgcn_mfma_f32_16x16x32_bf16(ahP, bl[c], accP[c], 0, 0, 0);
                accP[c] = __builtin_amdgcn_mfma_f32_16x16x32_bf16(alP, bh[c], accP[c], 0, 0, 0);
            }
            long aoffD = (((long)ks * 16 + 8 + wv) * 64 + lane) * 8;
            short8 ahD = *(const short8*)(AnH + aoffD);
            short8 alD = *(const short8*)(AnL + aoffD);
#pragma unroll
            for (int c = 0; c < 3; ++c) {
                accD[c] = __builtin_amdgcn_mfma_f32_16x16x32_bf16(ahD, bh[c], accD[c], 0, 0, 0);
                accD[c] = __builtin_amdgcn_mfma_f32_16x16x32_bf16(ahD, bl[c], accD[c], 0, 0, 0);
                accD[c] = __builtin_amdgcn_mfma_f32_16x16x32_bf16(alD, bh[c], accD[c], 0, 0, 0);
            }
        }
        int obase = 16 * wv + ((lane >> 4) << 2);
        float Pv[3][4];
#pragma unroll
        for (int r = 0; r < 4; ++r) {
            float P[3], D[3];
#pragma unroll
            for (int c = 0; c < 3; ++c) { P[c] = accP[c][r]; D[c] = accD[c][r]; }
            float dot = P[0] * D[0] + P[1] * D[1] + P[2] * D[2];
            float dsq = D[0] * D[0] + D[1] * D[1] + D[2] * D[2];
            if (dot < 0.0f) {
                float s = dot / (dsq + 1e-6f);
                P[0] -= s * D[0]; P[1] -= s * D[1]; P[2] -= s * D[2];
            }
            Pv[0][r] = P[0]; Pv[1][r] = P[1]; Pv[2][r] = P[2];
        }
#pragma unroll
        for (int c = 0; c < 3; ++c) {
            unsigned short hs[4], ls[4];
#pragma unroll
            for (int r = 0; r < 4; ++r) {
                hs[r] = f2bf(Pv[c][r]);
                ls[r] = f2bf(Pv[c][r] - bf2f(hs[r]));
            }
            long ooff = ((long)(b * 3 + c) * N + ncol) * 128 + obase;
            *(ushort4*)(y1h + ooff) = make_ushort4(hs[0], hs[1], hs[2], hs[3]);
            *(ushort4*)(y1l + ooff) = make_ushort4(ls[0], ls[1], ls[2], ls[3]);
#pragma unroll
            for (int r = 0; r < 4; ++r) {
                float v = Pv[c][r];
                v += __shfl_xor(v, 1);
                v += __shfl_xor(v, 2);
                v += __shfl_xor(v, 4);
                v += __shfl_xor(v, 8);
                if ((lane & 15) == 0)
                    part[((long)(b * 3 + c) * 256 + tile * 2 + ng) * 128 + (obase + r)] = v;
            }
        }
    }
}

// ---------------- fused yg reduce + bias: 6 blocks (b*3+c), 1024 threads ----------------
__global__ __launch_bounds__(1024) void ygredbias_kernel(const float* __restrict__ part,
                                                         const float* __restrict__ Wg,
                                                         const float* __restrict__ Ug,
                                                         float* __restrict__ biasP,
                                                         float* __restrict__ biasD) {
    __shared__ float red[8][128];
    __shared__ float ygs[128];
    int bc = blockIdx.x;
    int t = threadIdx.x;
    int o = t & 127, g = t >> 7;
    float s = 0.f;
    for (int seg = g * 32; seg < g * 32 + 32; ++seg)
        s += part[((long)bc * 256 + seg) * 128 + o];
    red[g][o] = s;
    __syncthreads();
    if (t < 128) {
        float r = 0.f;
#pragma unroll
        for (int k = 0; k < 8; ++k) r += red[k][t];
        ygs[t] = r * (1.0f / 4096.0f);
    }
    __syncthreads();
    if (t < 256) {
        int oo = t & 127; bool isD = t >= 128;
        const float* row = (isD ? Ug : Wg) + oo * 256 + 128;
        float s2 = 0.f;
        for (int i = 0; i < 128; ++i) s2 = fmaf(row[i], ygs[i], s2);
        int b = bc / 3, c = bc % 3;
        (isD ? biasD : biasP)[((long)(b * 128 + oo)) * 3 + c] = s2;
    }
}

// ---------------- out0 finalize: 6 blocks (b*3+c), 1024 threads ----------------
__global__ __launch_bounds__(1024) void out0red_kernel(const float* __restrict__ part,
                                                       float* __restrict__ out0) {
    __shared__ float red[8][128];
    int bc = blockIdx.x;
    int t = threadIdx.x;
    int o = t & 127, g = t >> 7;
    float s = 0.f;
    for (int seg = g * 32; seg < g * 32 + 32; ++seg)
        s += part[((long)bc * 256 + seg) * 128 + o];
    red[g][o] = s;
    __syncthreads();
    if (t < 128) {
        float r = 0.f;
#pragma unroll
        for (int k = 0; k < 8; ++k) r += red[k][t];
        int b = bc / 3, c = bc % 3;
        out0[((long)(b * 128) + t) * 3 + c] = r * (1.0f / 4096.0f);
    }
}

extern "C" void kernel_launch(void* const* d_in, const int* in_sizes, int n_in,
                              void* d_out, int out_size, void* d_ws, size_t ws_size,
                              hipStream_t stream) {
    const float* x    = (const float*)d_in[0];
    const float* Win  = (const float*)d_in[1];
    const float* Uin  = (const float*)d_in[2];
    const float* Wl   = (const float*)d_in[3];
    const float* Ul   = (const float*)d_in[4];
    const float* Wg   = (const float*)d_in[5];
    const float* Ug   = (const float*)d_in[6];
    const float* Wout = (const float*)d_in[7];

    const int B = 2, N = 4096, H = 128;
    float* out0 = (float*)d_out;                 // (B,128,3) mean
    float* out1 = out0 + (long)B * H * 3;        // (B,128,3,N) fp32

    float* ws = (float*)d_ws;
    long off = 0;
    float4* pts4 = (float4*)ws;                  off += (long)B * N * 4;
    int* idx = (int*)(ws + off);                 off += (long)B * N * 16;
    const long ACT = (long)B * 3 * N * H;        // ushort count
    unsigned short* y1h = (unsigned short*)(ws + off);  off += ACT / 2;
    unsigned short* y1l = (unsigned short*)(ws + off);  off += ACT / 2;
    unsigned short* Aph = (unsigned short*)(ws + off);  off += 327680 / 2;
    unsigned short* Apl = (unsigned short*)(ws + off);  off += 327680 / 2;
    float* part  = ws + off;                     off += 6L * 256 * 128;
    float* biasP = ws + off;                     off += B * H * 3;
    float* biasD = ws + off;                     off += B * H * 3;
    // ~15 MB of workspace

    setup_kernel<<<1280, 256, 0, stream>>>(x, pts4, Wl, Ul, Wg, Ug, Wout, Aph, Apl, N, B);
    knn_kernel<<<B * (N / 16), 1024, 0, stream>>>(pts4, idx, N);

    // edge features + layer-0 input GEMM fused (f0 lives in LDS only)
    edgegemm0_kernel<<<256, 1024, 0, stream>>>(pts4, idx, Win, Uin,
                                               Aph, Apl, y1h, y1l, part, N);

    for (int l = 0; l < 4; ++l) {
        ygredbias_kernel<<<6, 1024, 0, stream>>>(part,
            Wg + (long)l * H * 256, Ug + (long)l * H * 256, biasP, biasD);
        long aG = (long)(4 + l) * 32768;
        long aO = 262144 + (long)l * 16384;
        if (l < 3) {
            fused_kernel<true><<<256, 1024, 0, stream>>>(
                Aph, Apl, aG, aO, (long)(l + 1) * 32768,
                y1h, y1l, biasP, biasD, out1, part, l > 0 ? 1 : 0);
        } else {
            fused_kernel<false><<<256, 1024, 0, stream>>>(
                Aph, Apl, aG, aO, 0L,
                y1h, y1l, biasP, biasD, out1, part, 1);
        }
    }
    out0red_kernel<<<6, 1024, 0, stream>>>(part, out0);
}

// Round 18
// 230.871 us; speedup vs baseline: 1.1128x; 1.0034x over previous
//
#include <hip/hip_runtime.h>
#include <hip/hip_bf16.h>
#include <cfloat>

// VecPointNet on MI355X, round 18: exact revert to r16 (231.7us, absmax 3.9e-3).
// r17's single-bf16 activations failed correctness (9.77e-2 > 2.625e-2):
// 6 stages of activation rounding compound through the LNA branch. bf16 hi/lo
// activations (bf16x3 products) are the verified minimum precision.

typedef __attribute__((ext_vector_type(8))) short short8;
typedef __attribute__((ext_vector_type(4))) float f32x4;

__device__ __forceinline__ unsigned short f2bf(float f) {
    union { float f; unsigned u; } v; v.f = f;
    unsigned r = v.u + 0x7fffu + ((v.u >> 16) & 1u);
    return (unsigned short)(r >> 16);
}
__device__ __forceinline__ float bf2f(unsigned short h) {
    union { unsigned u; float f; } v; v.u = ((unsigned)h) << 16;
    return v.f;
}

// ---------------- setup: prep (pts4) + weight pack ----------------
__global__ __launch_bounds__(256) void setup_kernel(const float* __restrict__ x,
                                                    float4* __restrict__ pts4,
                                                    const float* __restrict__ Wl,
                                                    const float* __restrict__ Ul,
                                                    const float* __restrict__ Wg,
                                                    const float* __restrict__ Ug,
                                                    const float* __restrict__ Wout,
                                                    unsigned short* __restrict__ Ah,
                                                    unsigned short* __restrict__ Al,
                                                    int N, int B) {
    int t = blockIdx.x * 256 + threadIdx.x;     // 0..327679
    if (t < B * N) {
        int b = t / N, n = t - b * N;
        const float* xb = x + (long)b * 3 * N;
        float px = xb[n], py = xb[N + n], pz = xb[2 * N + n];
        pts4[t] = make_float4(px, py, pz, px * px + py * py + pz * pz);
    }
    int g, r, M; long base;
    if (t < 262144) { g = t >> 15; r = t & 32767; M = 256; base = (long)g << 15; }
    else { int t2 = t - 262144; g = 8 + (t2 >> 14); r = t2 & 16383; M = 128;
           base = 262144 + (long)(g - 8) * 16384; }
    int MF = M >> 4;
    int ks = r / (MF * 512);
    int mf = (r >> 9) % MF;
    int lane = (r >> 3) & 63;
    int j = r & 7;
    int m = mf * 16 + (lane & 15);
    int k = ks * 32 + ((lane >> 4) << 3) + j;
    const float* src; int ldw; int row;
    if (g < 4) {
        ldw = 128; row = m & 127;
        src = (m < 128) ? (Wl + (long)g * 128 * 128) : (Ul + (long)g * 128 * 128);
    } else if (g < 8) {
        ldw = 256; row = m & 127;
        int l = g - 4;
        src = (m < 128) ? (Wg + (long)l * 128 * 256) : (Ug + (long)l * 128 * 256);
    } else {
        ldw = 512; row = m;
        src = Wout + (g - 8) * 128;
    }
    float v = src[(long)row * ldw + k];
    unsigned short h = f2bf(v);
    Ah[base + r] = h;
    Al[base + r] = f2bf(v - bf2f(h));
}

// ---------------- knn (r13): bitonic-init chunk 0, stale-T DPP inserts ----------------
__global__ __launch_bounds__(1024) void knn_kernel(const float4* __restrict__ pts4,
                                                   int* __restrict__ idxOut, int N) {
    __shared__ float4 cbuf[4096];   // 64 KB
    int t = threadIdx.x;
    int tilesPerB = N / 16;
    int b = blockIdx.x / tilesPerB;
    int q = (blockIdx.x % tilesPerB) * 16 + (t >> 6);
    int lane = t & 63;

    for (int i = t; i < N; i += 1024) cbuf[i] = pts4[b * N + i];
    __syncthreads();

    float4 Q = cbuf[q];
    unsigned ku; int ki;                         // lanes 0..15: sorted top-16 list

    // ---- chunk 0: 64-lane bitonic sort on exact key = u*4096 + idx ----
    {
        float4 C = cbuf[lane];
        float dot = Q.x * C.x + Q.y * C.y + Q.z * C.z;
        float d2 = Q.w + C.w - 2.0f * dot;        // same formula as reference
        unsigned u = __float_as_uint(d2);
        u ^= (unsigned)((int)u >> 31) | 0x80000000u;
        double key = (double)u * 4096.0 + (double)lane;
#pragma unroll
        for (int k = 2; k <= 64; k <<= 1) {
#pragma unroll
            for (int j = k >> 1; j > 0; j >>= 1) {
                double other = __shfl_xor(key, j);
                bool takeMin = (((lane & j) == 0) == ((lane & k) == 0));
                double mn = fmin(key, other), mx = fmax(key, other);
                key = takeMin ? mn : mx;
            }
        }
        long long kl = (long long)key;            // exact (key < 2^44)
        ki = (int)(kl & 4095);
        ku = (unsigned)(kl >> 12);
    }
    unsigned Tu = (unsigned)__builtin_amdgcn_readlane((int)ku, 15);

    for (int c0 = 64; c0 < N; c0 += 64) {
        float4 C = cbuf[c0 + lane];
        float dot = Q.x * C.x + Q.y * C.y + Q.z * C.z;
        float d2 = Q.w + C.w - 2.0f * dot;        // same formula as reference
        unsigned u = __float_as_uint(d2);
        u ^= (unsigned)((int)u >> 31) | 0x80000000u;
        int ci = c0 + lane;
        unsigned long long mask = __ballot(u <= Tu);
        while (mask) {
            int src = __ffsll(mask) - 1;
            mask &= mask - 1;
            unsigned vu = (unsigned)__builtin_amdgcn_readlane((int)u, src);
            int      vi = __builtin_amdgcn_readlane(ci, src);
            unsigned kum1 = (unsigned)__builtin_amdgcn_update_dpp(
                                (int)ku, (int)ku, 0x111, 0xF, 0xF, false);
            int      kim1 = __builtin_amdgcn_update_dpp(
                                ki, ki, 0x111, 0xF, 0xF, false);
            if (lane == 0) { kum1 = 0u; kim1 = (-2147483647 - 1); }
            bool lem1 = (vu < kum1) || (vu == kum1 && vi < kim1);  // v < k[j-1]
            bool ltj  = (vu < ku)   || (vu == ku   && vi < ki);    // v < k[j]
            unsigned knu = lem1 ? kum1 : (ltj ? vu : ku);
            int      kni = lem1 ? kim1 : (ltj ? vi : ki);
            if (lane < 16) { ku = knu; ki = kni; }
        }
        Tu = (unsigned)__builtin_amdgcn_readlane((int)ku, 15);
    }
    if (lane < 16) idxOut[(b * N + q) * 16 + lane] = ki;
}

// ---------------- edge + gemm0 merged, 1024 threads (16 waves, 1 frag-pair/wave) ----------------
__global__ __launch_bounds__(1024) void edgegemm0_kernel(
    const float4* __restrict__ pts4, const int* __restrict__ idx,
    const float* __restrict__ Win, const float* __restrict__ Uin,
    const unsigned short* __restrict__ Aph, const unsigned short* __restrict__ Apl,
    unsigned short* __restrict__ Oh, unsigned short* __restrict__ Ol,
    float* __restrict__ part, int N)
{
    __shared__ float4 nbuf[32][16];                 // 8 KB
    __shared__ float4 cpt[32];
    __shared__ unsigned short flds[2][3][2][2048];  // 48 KB, ylds layout
    int t = threadIdx.x;
    int lane = t & 63, w = t >> 6;                  // w 0..15
    int ng = w >> 3, wv = w & 7;
    int b = blockIdx.x >> 7;
    int tile = blockIdx.x & 127;
    int n0 = tile * 32;

    // ---- phase E: stage neighbors + centers ----
    if (t < 512) {
        int pl = t >> 4, k = t & 15;
        int nb = idx[(b * N + n0 + pl) * 16 + k];
        nbuf[pl][k] = pts4[b * N + nb];
    } else if (t < 544) {
        cpt[t - 512] = pts4[b * N + n0 + (t - 512)];
    }
    __syncthreads();
    {
        int o = t & 127, grp = t >> 7;              // grp 0..7, 4 points each
        float w0 = Win[o * 3], w1 = Win[o * 3 + 1], w2 = Win[o * 3 + 2];
        float u0 = Uin[o * 3], u1 = Uin[o * 3 + 1], u2 = Uin[o * 3 + 2];
        for (int pl = grp * 4; pl < grp * 4 + 4; ++pl) {
            float4 c4 = cpt[pl];
            float inv = 1.0f / fmaxf(sqrtf(c4.w), 1e-12f);
            float ax = c4.x * inv, ay = c4.y * inv, az = c4.z * inv;
            float a0 = 0.f, a1 = 0.f, a2 = 0.f;
            for (int k = 0; k < 16; ++k) {
                float4 nb = nbuf[pl][k];
                float cr0 = ay * nb.z - az * nb.y;
                float cr1 = az * nb.x - ax * nb.z;
                float cr2 = ax * nb.y - ay * nb.x;
                float df0 = nb.x - c4.x, df1 = nb.y - c4.y, df2 = nb.z - c4.z;
                float P0 = w0 * cr0 + w1 * df0 + w2 * c4.x;
                float P1 = w0 * cr1 + w1 * df1 + w2 * c4.y;
                float P2 = w0 * cr2 + w1 * df2 + w2 * c4.z;
                float D0 = u0 * cr0 + u1 * df0 + u2 * c4.x;
                float D1 = u0 * cr1 + u1 * df1 + u2 * c4.y;
                float D2 = u0 * cr2 + u1 * df2 + u2 * c4.z;
                float dot = P0 * D0 + P1 * D1 + P2 * D2;
                float dsq = D0 * D0 + D1 * D1 + D2 * D2;
                if (dot < 0.0f) {
                    float s = dot / (dsq + 1e-6f);
                    P0 -= s * D0; P1 -= s * D1; P2 -= s * D2;
                }
                a0 += P0; a1 += P1; a2 += P2;
            }
            float vals[3] = { a0 * (1.0f / 16.0f), a1 * (1.0f / 16.0f), a2 * (1.0f / 16.0f) };
            int ngg = pl >> 4, col = pl & 15;
            int li = ((o >> 3) << 7) + (col << 3) + (o & 7);
#pragma unroll
            for (int c = 0; c < 3; ++c) {
                unsigned short hh = f2bf(vals[c]);
                flds[ngg][c][0][li] = hh;
                flds[ngg][c][1][li] = f2bf(vals[c] - bf2f(hh));
            }
        }
    }
    __syncthreads();

    // ---- phase G: y1 = LNA(Wl0 f0, Ul0 f0) + yg partials (B from flds) ----
    int ncol = tile * 32 + ng * 16 + (lane & 15);
    f32x4 accP[3] = {};
    f32x4 accD[3] = {};
#pragma unroll
    for (int ks = 0; ks < 4; ++ks) {
        short8 bh[3], bl[3];
        int li = (((ks << 2) + (lane >> 4)) << 7) + ((lane & 15) << 3);
#pragma unroll
        for (int c = 0; c < 3; ++c) {
            bh[c] = *(const short8*)&flds[ng][c][0][li];
            bl[c] = *(const short8*)&flds[ng][c][1][li];
        }
        long aoffP = (((long)ks * 16 + wv) * 64 + lane) * 8;
        short8 ahP = *(const short8*)(Aph + aoffP);
        short8 alP = *(const short8*)(Apl + aoffP);
#pragma unroll
        for (int c = 0; c < 3; ++c) {
            accP[c] = __builtin_amdgcn_mfma_f32_16x16x32_bf16(ahP, bh[c], accP[c], 0, 0, 0);
            accP[c] = __builtin_amdgcn_mfma_f32_16x16x32_bf16(ahP, bl[c], accP[c], 0, 0, 0);
            accP[c] = __builtin_amdgcn_mfma_f32_16x16x32_bf16(alP, bh[c], accP[c], 0, 0, 0);
        }
        long aoffD = (((long)ks * 16 + 8 + wv) * 64 + lane) * 8;
        short8 ahD = *(const short8*)(Aph + aoffD);
        short8 alD = *(const short8*)(Apl + aoffD);
#pragma unroll
        for (int c = 0; c < 3; ++c) {
            accD[c] = __builtin_amdgcn_mfma_f32_16x16x32_bf16(ahD, bh[c], accD[c], 0, 0, 0);
            accD[c] = __builtin_amdgcn_mfma_f32_16x16x32_bf16(ahD, bl[c], accD[c], 0, 0, 0);
            accD[c] = __builtin_amdgcn_mfma_f32_16x16x32_bf16(alD, bh[c], accD[c], 0, 0, 0);
        }
    }

    int obase = 16 * wv + ((lane >> 4) << 2);
    float Pv[3][4];
#pragma unroll
    for (int r = 0; r < 4; ++r) {
        float P[3], D[3];
#pragma unroll
        for (int c = 0; c < 3; ++c) { P[c] = accP[c][r]; D[c] = accD[c][r]; }
        float dot = P[0] * D[0] + P[1] * D[1] + P[2] * D[2];
        float dsq = D[0] * D[0] + D[1] * D[1] + D[2] * D[2];
        if (dot < 0.0f) {
            float s = dot / (dsq + 1e-6f);
            P[0] -= s * D[0]; P[1] -= s * D[1]; P[2] -= s * D[2];
        }
        Pv[0][r] = P[0]; Pv[1][r] = P[1]; Pv[2][r] = P[2];
    }
#pragma unroll
    for (int c = 0; c < 3; ++c) {
        unsigned short hs[4], ls[4];
#pragma unroll
        for (int r = 0; r < 4; ++r) {
            hs[r] = f2bf(Pv[c][r]);
            ls[r] = f2bf(Pv[c][r] - bf2f(hs[r]));
        }
        long ooff = ((long)(b * 3 + c) * N + ncol) * 128 + obase;
        *(ushort4*)(Oh + ooff) = make_ushort4(hs[0], hs[1], hs[2], hs[3]);
        *(ushort4*)(Ol + ooff) = make_ushort4(ls[0], ls[1], ls[2], ls[3]);
#pragma unroll
        for (int r = 0; r < 4; ++r) {
            float v = Pv[c][r];
            v += __shfl_xor(v, 1);
            v += __shfl_xor(v, 2);
            v += __shfl_xor(v, 4);
            v += __shfl_xor(v, 8);
            if ((lane & 15) == 0)
                part[((long)(b * 3 + c) * 256 + tile * 2 + ng) * 128 + (obase + r)] = v;
        }
    }
}

// ---------------- fused, 1024 threads (16 waves, 1 frag-pair/wave) ----------------
template<bool HASNEXT>
__global__ __launch_bounds__(1024) void fused_kernel(
    const unsigned short* __restrict__ Aph, const unsigned short* __restrict__ Apl,
    long aOffG, long aOffOut, long aOffNext,
    unsigned short* __restrict__ y1h, unsigned short* __restrict__ y1l,
    const float* __restrict__ biasP, const float* __restrict__ biasD,
    float* __restrict__ Ofp, float* __restrict__ part, int accum)
{
    const int N = 4096;
    __shared__ unsigned short ylds[2][3][2][2048];   // 48 KB
    int t = threadIdx.x;
    int lane = t & 63, w = t >> 6;                   // w 0..15
    int ng = w >> 3, wv = w & 7;
    int b = blockIdx.x >> 7;
    int tile = blockIdx.x & 127;
    int ncol = tile * 32 + ng * 16 + (lane & 15);
    int kq = (lane >> 4) << 3;

    // ---------- phase 1: y2 = LNA(Wg y1 + biasP, Ug y1 + biasD) -> ylds ----------
    {
        f32x4 accP[3] = {};
        f32x4 accD[3] = {};
        const unsigned short* AhB = Aph + aOffG;
        const unsigned short* AlB = Apl + aOffG;
#pragma unroll
        for (int ks = 0; ks < 4; ++ks) {
            short8 bh[3], bl[3];
#pragma unroll
            for (int c = 0; c < 3; ++c) {
                long boff = ((long)(b * 3 + c) * N + ncol) * 128 + ks * 32 + kq;
                bh[c] = *(const short8*)(y1h + boff);
                bl[c] = *(const short8*)(y1l + boff);
            }
            long aoffP = (((long)ks * 16 + wv) * 64 + lane) * 8;
            short8 ahP = *(const short8*)(AhB + aoffP);
            short8 alP = *(const short8*)(AlB + aoffP);
#pragma unroll
            for (int c = 0; c < 3; ++c) {
                accP[c] = __builtin_amdgcn_mfma_f32_16x16x32_bf16(ahP, bh[c], accP[c], 0, 0, 0);
                accP[c] = __builtin_amdgcn_mfma_f32_16x16x32_bf16(ahP, bl[c], accP[c], 0, 0, 0);
                accP[c] = __builtin_amdgcn_mfma_f32_16x16x32_bf16(alP, bh[c], accP[c], 0, 0, 0);
            }
            long aoffD = (((long)ks * 16 + 8 + wv) * 64 + lane) * 8;
            short8 ahD = *(const short8*)(AhB + aoffD);
            short8 alD = *(const short8*)(AlB + aoffD);
#pragma unroll
            for (int c = 0; c < 3; ++c) {
                accD[c] = __builtin_amdgcn_mfma_f32_16x16x32_bf16(ahD, bh[c], accD[c], 0, 0, 0);
                accD[c] = __builtin_amdgcn_mfma_f32_16x16x32_bf16(ahD, bl[c], accD[c], 0, 0, 0);
                accD[c] = __builtin_amdgcn_mfma_f32_16x16x32_bf16(alD, bh[c], accD[c], 0, 0, 0);
            }
        }
        int obase = 16 * wv + ((lane >> 4) << 2);
        float Pv[3][4];
#pragma unroll
        for (int r = 0; r < 4; ++r) {
            int o = obase + r;
            float P[3], D[3];
#pragma unroll
            for (int c = 0; c < 3; ++c) {
                long bb = ((long)(b * 128 + o)) * 3 + c;
                P[c] = accP[c][r] + biasP[bb];
                D[c] = accD[c][r] + biasD[bb];
            }
            float dot = P[0] * D[0] + P[1] * D[1] + P[2] * D[2];
            float dsq = D[0] * D[0] + D[1] * D[1] + D[2] * D[2];
            if (dot < 0.0f) {
                float s = dot / (dsq + 1e-6f);
                P[0] -= s * D[0]; P[1] -= s * D[1]; P[2] -= s * D[2];
            }
            Pv[0][r] = P[0]; Pv[1][r] = P[1]; Pv[2][r] = P[2];
        }
#pragma unroll
        for (int c = 0; c < 3; ++c) {
            unsigned short hs[4], ls[4];
#pragma unroll
            for (int r = 0; r < 4; ++r) {
                hs[r] = f2bf(Pv[c][r]);
                ls[r] = f2bf(Pv[c][r] - bf2f(hs[r]));
            }
            int li = ((obase >> 3) << 7) + ((lane & 15) << 3) + (obase & 7);
            *(ushort4*)&ylds[ng][c][0][li] = make_ushort4(hs[0], hs[1], hs[2], hs[3]);
            *(ushort4*)&ylds[ng][c][1][li] = make_ushort4(ls[0], ls[1], ls[2], ls[3]);
        }
    }
    __syncthreads();

    // ---------- phase 2: out1 (+)= Wout_l @ y2 ; !HASNEXT: emit out0 partials ----------
    {
        f32x4 accO[3] = {};
        const unsigned short* AoH = Aph + aOffOut;
        const unsigned short* AoL = Apl + aOffOut;
#pragma unroll
        for (int ks = 0; ks < 4; ++ks) {
            short8 yh[3], yl[3];
            int li = (((ks << 2) + (lane >> 4)) << 7) + ((lane & 15) << 3);
#pragma unroll
            for (int c = 0; c < 3; ++c) {
                yh[c] = *(const short8*)&ylds[ng][c][0][li];
                yl[c] = *(const short8*)&ylds[ng][c][1][li];
            }
            long aoff = (((long)ks * 8 + wv) * 64 + lane) * 8;
            short8 ah = *(const short8*)(AoH + aoff);
            short8 al = *(const short8*)(AoL + aoff);
#pragma unroll
            for (int c = 0; c < 3; ++c) {
                accO[c] = __builtin_amdgcn_mfma_f32_16x16x32_bf16(ah, yh[c], accO[c], 0, 0, 0);
                accO[c] = __builtin_amdgcn_mfma_f32_16x16x32_bf16(ah, yl[c], accO[c], 0, 0, 0);
                accO[c] = __builtin_amdgcn_mfma_f32_16x16x32_bf16(al, yh[c], accO[c], 0, 0, 0);
            }
        }
        int obase = 16 * wv + ((lane >> 4) << 2);
        float Ov[3][4];
#pragma unroll
        for (int r = 0; r < 4; ++r) {
            int o = obase + r;
#pragma unroll
            for (int c = 0; c < 3; ++c) {
                long off = ((long)(b * 128 + o) * 3 + c) * N + ncol;
                float v = accO[c][r];
                if (accum) v += Ofp[off];
                Ofp[off] = v;
                Ov[c][r] = v;
            }
        }
        if (!HASNEXT) {
#pragma unroll
            for (int c = 0; c < 3; ++c) {
#pragma unroll
                for (int r = 0; r < 4; ++r) {
                    float v = Ov[c][r];
                    v += __shfl_xor(v, 1);
                    v += __shfl_xor(v, 2);
                    v += __shfl_xor(v, 4);
                    v += __shfl_xor(v, 8);
                    if ((lane & 15) == 0)
                        part[((long)(b * 3 + c) * 256 + tile * 2 + ng) * 128 + (obase + r)] = v;
                }
            }
        }
    }

    // ---------- phase 3 (HASNEXT): y1' = LNA(Wl' y2, Ul' y2) -> y1 + yg partials ----------
    if (HASNEXT) {
        f32x4 accP[3] = {};
        f32x4 accD[3] = {};
        const unsigned short* AnH = Aph + aOffNext;
        const unsigned short* AnL = Apl + aOffNext;
#pragma unroll
        for (int ks = 0; ks < 4; ++ks) {
            short8 bh[3], bl[3];
            int li = (((ks << 2) + (lane >> 4)) << 7) + ((lane & 15) << 3);
#pragma unroll
            for (int c = 0; c < 3; ++c) {
                bh[c] = *(const short8*)&ylds[ng][c][0][li];
                bl[c] = *(const short8*)&ylds[ng][c][1][li];
            }
            long aoffP = (((long)ks * 16 + wv) * 64 + lane) * 8;
            short8 ahP = *(const short8*)(AnH + aoffP);
            short8 alP = *(const short8*)(AnL + aoffP);
#pragma unroll
            for (int c = 0; c < 3; ++c) {
                accP[c] = __builtin_amdgcn_mfma_f32_16x16x32_bf16(ahP, bh[c], accP[c], 0, 0, 0);
                accP[c] = __builtin_amdgcn_mfma_f32_16x16x32_bf16(ahP, bl[c], accP[c], 0, 0, 0);
                accP[c] = __builtin_amdgcn_mfma_f32_16x16x32_bf16(alP, bh[c], accP[c], 0, 0, 0);
            }
            long aoffD = (((long)ks * 16 + 8 + wv) * 64 + lane) * 8;
            short8 ahD = *(const short8*)(AnH + aoffD);
            short8 alD = *(const short8*)(AnL + aoffD);
#pragma unroll
            for (int c = 0; c < 3; ++c) {
                accD[c] = __builtin_amdgcn_mfma_f32_16x16x32_bf16(ahD, bh[c], accD[c], 0, 0, 0);
                accD[c] = __builtin_amdgcn_mfma_f32_16x16x32_bf16(ahD, bl[c], accD[c], 0, 0, 0);
                accD[c] = __builtin_amdgcn_mfma_f32_16x16x32_bf16(alD, bh[c], accD[c], 0, 0, 0);
            }
        }
        int obase = 16 * wv + ((lane >> 4) << 2);
        float Pv[3][4];
#pragma unroll
        for (int r = 0; r < 4; ++r) {
            float P[3], D[3];
#pragma unroll
            for (int c = 0; c < 3; ++c) { P[c] = accP[c][r]; D[c] = accD[c][r]; }
            float dot = P[0] * D[0] + P[1] * D[1] + P[2] * D[2];
            float dsq = D[0] * D[0] + D[1] * D[1] + D[2] * D[2];
            if (dot < 0.0f) {
                float s = dot / (dsq + 1e-6f);
                P[0] -= s * D[0]; P[1] -= s * D[1]; P[2] -= s * D[2];
            }
            Pv[0][r] = P[0]; Pv[1][r] = P[1]; Pv[2][r] = P[2];
        }
#pragma unroll
        for (int c = 0; c < 3; ++c) {
            unsigned short hs[4], ls[4];
#pragma unroll
            for (int r = 0; r < 4; ++r) {
                hs[r] = f2bf(Pv[c][r]);
                ls[r] = f2bf(Pv[c][r] - bf2f(hs[r]));
            }
            long ooff = ((long)(b * 3 + c) * N + ncol) * 128 + obase;
            *(ushort4*)(y1h + ooff) = make_ushort4(hs[0], hs[1], hs[2], hs[3]);
            *(ushort4*)(y1l + ooff) = make_ushort4(ls[0], ls[1], ls[2], ls[3]);
#pragma unroll
            for (int r = 0; r < 4; ++r) {
                float v = Pv[c][r];
                v += __shfl_xor(v, 1);
                v += __shfl_xor(v, 2);
                v += __shfl_xor(v, 4);
                v += __shfl_xor(v, 8);
                if ((lane & 15) == 0)
                    part[((long)(b * 3 + c) * 256 + tile * 2 + ng) * 128 + (obase + r)] = v;
            }
        }
    }
}

// ---------------- fused yg reduce + bias: 6 blocks (b*3+c), 1024 threads ----------------
__global__ __launch_bounds__(1024) void ygredbias_kernel(const float* __restrict__ part,
                                                         const float* __restrict__ Wg,
                                                         const float* __restrict__ Ug,
                                                         float* __restrict__ biasP,
                                                         float* __restrict__ biasD) {
    __shared__ float red[8][128];
    __shared__ float ygs[128];
    int bc = blockIdx.x;
    int t = threadIdx.x;
    int o = t & 127, g = t >> 7;
    float s = 0.f;
    for (int seg = g * 32; seg < g * 32 + 32; ++seg)
        s += part[((long)bc * 256 + seg) * 128 + o];
    red[g][o] = s;
    __syncthreads();
    if (t < 128) {
        float r = 0.f;
#pragma unroll
        for (int k = 0; k < 8; ++k) r += red[k][t];
        ygs[t] = r * (1.0f / 4096.0f);
    }
    __syncthreads();
    if (t < 256) {
        int oo = t & 127; bool isD = t >= 128;
        const float* row = (isD ? Ug : Wg) + oo * 256 + 128;
        float s2 = 0.f;
        for (int i = 0; i < 128; ++i) s2 = fmaf(row[i], ygs[i], s2);
        int b = bc / 3, c = bc % 3;
        (isD ? biasD : biasP)[((long)(b * 128 + oo)) * 3 + c] = s2;
    }
}

// ---------------- out0 finalize: 6 blocks (b*3+c), 1024 threads ----------------
__global__ __launch_bounds__(1024) void out0red_kernel(const float* __restrict__ part,
                                                       float* __restrict__ out0) {
    __shared__ float red[8][128];
    int bc = blockIdx.x;
    int t = threadIdx.x;
    int o = t & 127, g = t >> 7;
    float s = 0.f;
    for (int seg = g * 32; seg < g * 32 + 32; ++seg)
        s += part[((long)bc * 256 + seg) * 128 + o];
    red[g][o] = s;
    __syncthreads();
    if (t < 128) {
        float r = 0.f;
#pragma unroll
        for (int k = 0; k < 8; ++k) r += red[k][t];
        int b = bc / 3, c = bc % 3;
        out0[((long)(b * 128) + t) * 3 + c] = r * (1.0f / 4096.0f);
    }
}

extern "C" void kernel_launch(void* const* d_in, const int* in_sizes, int n_in,
                              void* d_out, int out_size, void* d_ws, size_t ws_size,
                              hipStream_t stream) {
    const float* x    = (const float*)d_in[0];
    const float* Win  = (const float*)d_in[1];
    const float* Uin  = (const float*)d_in[2];
    const float* Wl   = (const float*)d_in[3];
    const float* Ul   = (const float*)d_in[4];
    const float* Wg   = (const float*)d_in[5];
    const float* Ug   = (const float*)d_in[6];
    const float* Wout = (const float*)d_in[7];

    const int B = 2, N = 4096, H = 128;
    float* out0 = (float*)d_out;                 // (B,128,3) mean
    float* out1 = out0 + (long)B * H * 3;        // (B,128,3,N) fp32

    float* ws = (float*)d_ws;
    long off = 0;
    float4* pts4 = (float4*)ws;                  off += (long)B * N * 4;
    int* idx = (int*)(ws + off);                 off += (long)B * N * 16;
    const long ACT = (long)B * 3 * N * H;        // ushort count
    unsigned short* y1h = (unsigned short*)(ws + off);  off += ACT / 2;
    unsigned short* y1l = (unsigned short*)(ws + off);  off += ACT / 2;
    unsigned short* Aph = (unsigned short*)(ws + off);  off += 327680 / 2;
    unsigned short* Apl = (unsigned short*)(ws + off);  off += 327680 / 2;
    float* part  = ws + off;                     off += 6L * 256 * 128;
    float* biasP = ws + off;                     off += B * H * 3;
    float* biasD = ws + off;                     off += B * H * 3;
    // ~15 MB of workspace

    setup_kernel<<<1280, 256, 0, stream>>>(x, pts4, Wl, Ul, Wg, Ug, Wout, Aph, Apl, N, B);
    knn_kernel<<<B * (N / 16), 1024, 0, stream>>>(pts4, idx, N);

    // edge features + layer-0 input GEMM fused (f0 lives in LDS only)
    edgegemm0_kernel<<<256, 1024, 0, stream>>>(pts4, idx, Win, Uin,
                                               Aph, Apl, y1h, y1l, part, N);

    for (int l = 0; l < 4; ++l) {
        ygredbias_kernel<<<6, 1024, 0, stream>>>(part,
            Wg + (long)l * H * 256, Ug + (long)l * H * 256, biasP, biasD);
        long aG = (long)(4 + l) * 32768;
        long aO = 262144 + (long)l * 16384;
        if (l < 3) {
            fused_kernel<true><<<256, 1024, 0, stream>>>(
                Aph, Apl, aG, aO, (long)(l + 1) * 32768,
                y1h, y1l, biasP, biasD, out1, part, l > 0 ? 1 : 0);
        } else {
            fused_kernel<false><<<256, 1024, 0, stream>>>(
                Aph, Apl, aG, aO, 0L,
                y1h, y1l, biasP, biasD, out1, part, 1);
        }
    }
    out0red_kernel<<<6, 1024, 0, stream>>>(part, out0);
}